// Round 8
// baseline (921.208 us; speedup 1.0000x reference)
//
#include <hip/hip_runtime.h>
#include <math.h>

#define BATCH 4
#define SEQ   2048
#define CDIM  2048
#define NH    16
#define NG    4
#define HD    128
#define MTOT  (BATCH*SEQ)   // 8192
#define KVD   (NG*HD)       // 512

typedef __attribute__((ext_vector_type(8))) short     bf16x8;
typedef __attribute__((ext_vector_type(8))) unsigned short u16x8;
typedef __attribute__((ext_vector_type(4))) float     f32x4;
typedef unsigned short ushort_t;

static __device__ __forceinline__ unsigned short f2bf(float f) {
  unsigned u = __float_as_uint(f);
  u += 0x7FFF + ((u >> 16) & 1);          // round-to-nearest-even
  return (unsigned short)(u >> 16);
}
static __device__ __forceinline__ float bf2f(unsigned short h) {
  return __uint_as_float(((unsigned)h) << 16);
}

// async 16B global->LDS (linear dest = wave base + lane*16)
#define GLOAD_LDS16(gp, lp)                                                        \
  __builtin_amdgcn_global_load_lds((const __attribute__((address_space(1))) void*)(gp), \
                                   (__attribute__((address_space(3))) void*)(lp),  \
                                   16, 0, 0)

// =====================================================================
// f32 -> bf16 convert (8 elems/thread)
// =====================================================================
__global__ __launch_bounds__(256) void cvt_f32_bf16(
    const float* __restrict__ s, ushort_t* __restrict__ d, int n8)
{
  int i = blockIdx.x * 256 + threadIdx.x;
  if (i >= n8) return;
  const float4* p = (const float4*)(s + (size_t)i * 8);
  float4 a = p[0], b = p[1];
  u16x8 o;
  o[0] = f2bf(a.x); o[1] = f2bf(a.y); o[2] = f2bf(a.z); o[3] = f2bf(a.w);
  o[4] = f2bf(b.x); o[5] = f2bf(b.y); o[6] = f2bf(b.z); o[7] = f2bf(b.w);
  *(u16x8*)(d + (size_t)i * 8) = o;
}

// =====================================================================
// bf16 GEMM (m97 structure): C = A[M,K] @ B[N,K]^T
// OUTMODE: 0 = bf16 C[M,N]; 1 = f32 C[M,N]; 2 = bf16 C^T[N,M] (V^T)
// =====================================================================
template<int OUTMODE>
__global__ __launch_bounds__(256) void gemm_bt_bf16(
    const ushort_t* __restrict__ A, const ushort_t* __restrict__ B,
    void* __restrict__ C, int M, int N, int K)
{
  __shared__ ushort_t As[128 * 32];
  __shared__ ushort_t Bs[128 * 32];
  const int tid  = threadIdx.x;
  const int lane = tid & 63, w = tid >> 6;
  const int wm = (w >> 1) * 64, wn = (w & 1) * 64;
  const int bm = blockIdx.x * 128, bn = blockIdx.y * 128;

  f32x4 acc[4][4];
#pragma unroll
  for (int m = 0; m < 4; ++m)
#pragma unroll
    for (int n = 0; n < 4; ++n) acc[m][n] = (f32x4){0.f, 0.f, 0.f, 0.f};

  const int srow = tid >> 2;            // 0..63
  const int scol = (tid & 3) * 8;
  const ushort_t* Ap = A + (size_t)(bm + srow) * K + scol;
  const ushort_t* Bp = B + (size_t)(bn + srow) * K + scol;

  const int fr = lane & 15, fg = lane >> 4;

  for (int k0 = 0; k0 < K; k0 += 32) {
    GLOAD_LDS16(Ap + k0,                  As + tid * 8);
    GLOAD_LDS16(Ap + (size_t)64 * K + k0, As + 2048 + tid * 8);
    GLOAD_LDS16(Bp + k0,                  Bs + tid * 8);
    GLOAD_LDS16(Bp + (size_t)64 * K + k0, Bs + 2048 + tid * 8);
    __syncthreads();

    bf16x8 av[4], bv[4];
#pragma unroll
    for (int m = 0; m < 4; ++m)
      av[m] = *(const bf16x8*)(As + (wm + m * 16 + fr) * 32 + fg * 8);
#pragma unroll
    for (int n = 0; n < 4; ++n)
      bv[n] = *(const bf16x8*)(Bs + (wn + n * 16 + fr) * 32 + fg * 8);
#pragma unroll
    for (int m = 0; m < 4; ++m)
#pragma unroll
      for (int n = 0; n < 4; ++n)
        acc[m][n] = __builtin_amdgcn_mfma_f32_16x16x32_bf16(av[m], bv[n], acc[m][n], 0, 0, 0);
    __syncthreads();
  }

  // C/D layout: col = lane&15, row = (lane>>4)*4 + reg  (m89-verified)
  if constexpr (OUTMODE == 2) {
    __shared__ ushort_t Ct[128 * 144];
#pragma unroll
    for (int m = 0; m < 4; ++m)
#pragma unroll
      for (int n = 0; n < 4; ++n)
#pragma unroll
        for (int r = 0; r < 4; ++r)
          Ct[(wn + n * 16 + fr) * 144 + wm + m * 16 + fg * 4 + r] = f2bf(acc[m][n][r]);
    __syncthreads();
    const int col_l = tid >> 1, part = tid & 1;
    ushort_t* dst = (ushort_t*)C + (size_t)(bn + col_l) * M + bm + part * 64;
#pragma unroll
    for (int j = 0; j < 8; ++j)
      *(bf16x8*)(dst + j * 8) = *(const bf16x8*)(Ct + col_l * 144 + part * 64 + j * 8);
  } else {
#pragma unroll
    for (int m = 0; m < 4; ++m)
#pragma unroll
      for (int n = 0; n < 4; ++n)
#pragma unroll
        for (int r = 0; r < 4; ++r) {
          const int row = bm + wm + m * 16 + fg * 4 + r;
          const int col = bn + wn + n * 16 + fr;
          if (OUTMODE == 1) ((float*)C)[(size_t)row * N + col] = acc[m][n][r];
          else              ((ushort_t*)C)[(size_t)row * N + col] = f2bf(acc[m][n][r]);
        }
  }
}

// =====================================================================
// RoPE: precomputed cos/sin table [SEQ][64] + vectorized bf16x8 apply
// =====================================================================
__global__ __launch_bounds__(256) void rope_table(
    float2* __restrict__ tab, const int* __restrict__ off)
{
  int idx = blockIdx.x * 256 + threadIdx.x;
  if (idx >= SEQ * 64) return;
  int t = idx >> 6, i = idx & 63;
  float ang = (float)(t + off[0]) * powf(10000.0f, -(float)i * (1.0f / 64.0f));
  tab[idx] = make_float2(cosf(ang), sinf(ang));
}

__global__ __launch_bounds__(256) void rope_apply(
    ushort_t* __restrict__ qf, ushort_t* __restrict__ kf,
    const float2* __restrict__ tab)
{
  int idx = blockIdx.x * 256 + threadIdx.x;      // row(8192) x head(20) x i8(8)
  if (idx >= MTOT * 20 * 8) return;
  const int i8 = idx & 7;
  int rem = idx >> 3;
  const int head = rem % 20, row = rem / 20;

  ushort_t* p = (head < NH)
      ? qf + (size_t)row * CDIM + head * HD + i8 * 8
      : kf + (size_t)row * KVD + (head - NH) * HD + i8 * 8;

  const int t = row & (SEQ - 1);
  const float2* tp = tab + t * 64 + i8 * 8;
  u16x8 lo = *(const u16x8*)p, hi = *(const u16x8*)(p + 64);
  u16x8 nlo, nhi;
#pragma unroll
  for (int j = 0; j < 8; ++j) {
    const float2 cs = tp[j];
    const float l = bf2f(lo[j]), h_ = bf2f(hi[j]);
    nlo[j] = f2bf(l * cs.x - h_ * cs.y);
    nhi[j] = f2bf(h_ * cs.x + l * cs.y);
  }
  *(u16x8*)p = nlo;
  *(u16x8*)(p + 64) = nhi;
}

// =====================================================================
// MFMA flash attention v3, causal GQA. 256 thr / 4 waves; BQ=128
// (32 q-rows/wave), BKV=64. Async-stage split (T14). Heavy-first
// q-block order (tail fix). Defer-max (T13, wave-wide). Lane-partial l
// (epilogue shfl-reduce). LDS: Ks 64x136 + Vt 128x72 + Ps 128x66 =
// 52736 B -> 3 blocks/CU with __launch_bounds__(256,3).
// =====================================================================
#define KPAD 136
#define VPAD 72
#define PPAD 66

__global__ __launch_bounds__(256, 3) void attn_mfma(
    const ushort_t* __restrict__ qf,  // [M, NH*HD]
    const ushort_t* __restrict__ kf,  // [M, NG*HD]
    const ushort_t* __restrict__ vT,  // [KVD, M]  (V^T: row = g*128+d, col = b*2048+s)
    ushort_t* __restrict__ yb)        // [M, NH*HD]
{
  __shared__ ushort_t Ks[64 * KPAD];
  __shared__ ushort_t Vt[128 * VPAD];
  __shared__ ushort_t Ps[128 * PPAD];

  const int tid  = threadIdx.x;
  const int lane = tid & 63, wq = tid >> 6;
  const int bh = blockIdx.x, b = bh >> 4, h = bh & 15, g = h >> 2;
  const int qb = (gridDim.y - 1 - blockIdx.y) * 128;   // heavy-first
  const int fr = lane & 15, fg = lane >> 4;
  const int wrow0 = qb + wq * 32;           // wave's first q-row

  // Q fragments in registers: 2 row-blocks x 4 d-steps
  bf16x8 qv[2][4];
#pragma unroll
  for (int rb = 0; rb < 2; ++rb) {
    const ushort_t* qp = qf + (size_t)(b * SEQ + wrow0 + rb * 16 + fr) * CDIM + h * HD + fg * 8;
#pragma unroll
    for (int ds = 0; ds < 4; ++ds) qv[rb][ds] = *(const bf16x8*)(qp + ds * 32);
  }

  f32x4 o[2][8];
#pragma unroll
  for (int rb = 0; rb < 2; ++rb)
#pragma unroll
    for (int n = 0; n < 8; ++n) o[rb][n] = (f32x4){0.f, 0.f, 0.f, 0.f};
  float mrow[2][4], lrow[2][4];             // lrow is LANE-PARTIAL (this lane's cols)
#pragma unroll
  for (int rb = 0; rb < 2; ++rb)
#pragma unroll
    for (int r = 0; r < 4; ++r) { mrow[rb][r] = -1e30f; lrow[rb][r] = 0.f; }

  const float K2 = 0.12751743671f;          // (1/sqrt(128)) * log2(e)
  const float RTHR = 62.0f;                 // defer-max threshold (raw); P <= 2^(62*K2) ~ 2^8
  const int nkv = qb / 64 + 2;

  const ushort_t* vtb0 = vT + (size_t)(g * HD) * MTOT + (size_t)b * SEQ;
  const ushort_t* kfb  = kf + (size_t)(b * SEQ) * KVD + g * HD;

  bf16x8 kpre[4], vpre[4];

  auto prefetch = [&](int s0n) {
#pragma unroll
    for (int it = 0; it < 4; ++it) {
      const int f4 = tid + it * 256;
      kpre[it] = *(const bf16x8*)(kfb + (size_t)(s0n + (f4 >> 4)) * KVD + (f4 & 15) * 8);
    }
#pragma unroll
    for (int it = 0; it < 4; ++it) {
      const int f4 = tid + it * 256;
      vpre[it] = *(const bf16x8*)(vtb0 + s0n + (size_t)(f4 >> 3) * MTOT + (f4 & 7) * 8);
    }
  };
  auto writetile = [&]() {
#pragma unroll
    for (int it = 0; it < 4; ++it) {
      const int f4 = tid + it * 256;
      *(bf16x8*)(Ks + (f4 >> 4) * KPAD + (f4 & 15) * 8) = kpre[it];
    }
#pragma unroll
    for (int it = 0; it < 4; ++it) {
      const int f4 = tid + it * 256;
      *(bf16x8*)(Vt + (f4 >> 3) * VPAD + (f4 & 7) * 8) = vpre[it];
    }
  };

  prefetch(0);
  writetile();
  __syncthreads();

  for (int kb = 0; kb < nkv; ++kb) {
    const int s0 = kb * 64;
    const bool last = (kb + 1 >= nkv);
    if (!last) prefetch(s0 + 64);          // overlap HBM latency with compute

    if (s0 <= wrow0 + 31) {                // wave-uniform: tile touches this wave's rows
      // ---- S = Q K^T
      f32x4 st[2][4];
#pragma unroll
      for (int rb = 0; rb < 2; ++rb)
#pragma unroll
        for (int n = 0; n < 4; ++n) st[rb][n] = (f32x4){0.f, 0.f, 0.f, 0.f};
      __builtin_amdgcn_s_setprio(1);
#pragma unroll
      for (int ds = 0; ds < 4; ++ds)
#pragma unroll
        for (int n = 0; n < 4; ++n) {
          bf16x8 kvf = *(const bf16x8*)(Ks + (n * 16 + fr) * KPAD + ds * 32 + fg * 8);
          st[0][n] = __builtin_amdgcn_mfma_f32_16x16x32_bf16(qv[0][ds], kvf, st[0][n], 0, 0, 0);
          st[1][n] = __builtin_amdgcn_mfma_f32_16x16x32_bf16(qv[1][ds], kvf, st[1][n], 0, 0, 0);
        }
      __builtin_amdgcn_s_setprio(0);

      // ---- pass 1: mask (in place) + per-row max (reduced over fr group)
      const bool nomask = (s0 + 63 <= wrow0);
      float mx_a[2][4];
      bool grew = false;
#pragma unroll
      for (int rb = 0; rb < 2; ++rb)
#pragma unroll
        for (int r = 0; r < 4; ++r) {
          const int grow = wrow0 + rb * 16 + fg * 4 + r;
          float mx = -1e30f;
#pragma unroll
          for (int n = 0; n < 4; ++n) {
            float v = st[rb][n][r];
            if (!nomask) {
              const int col = s0 + n * 16 + fr;
              v = (col <= grow) ? v : -1e30f;
              st[rb][n][r] = v;
            }
            mx = fmaxf(mx, v);
          }
          mx = fmaxf(mx, __shfl_xor(mx, 1, 64));
          mx = fmaxf(mx, __shfl_xor(mx, 2, 64));
          mx = fmaxf(mx, __shfl_xor(mx, 4, 64));
          mx = fmaxf(mx, __shfl_xor(mx, 8, 64));
          mx_a[rb][r] = mx;
          grew = grew || (mx > mrow[rb][r] + RTHR);
        }

      // ---- defer-max: rescale only if some row's max grew past threshold
      if (__any(grew)) {
#pragma unroll
        for (int rb = 0; rb < 2; ++rb)
#pragma unroll
          for (int r = 0; r < 4; ++r) {
            const float mnew = fmaxf(mrow[rb][r], mx_a[rb][r]);
            const float es = exp2f((mrow[rb][r] - mnew) * K2);
            lrow[rb][r] *= es;
            mrow[rb][r] = mnew;
#pragma unroll
            for (int n = 0; n < 8; ++n) o[rb][n][r] *= es;
          }
      }

      // ---- pass 2: P = exp2((S - m)*K2), lane-partial l, write Ps
#pragma unroll
      for (int rb = 0; rb < 2; ++rb)
#pragma unroll
        for (int r = 0; r < 4; ++r) {
          const float m = mrow[rb][r];
          float sum = 0.f;
          const int prow = (wq * 32 + rb * 16 + fg * 4 + r) * PPAD;
#pragma unroll
          for (int n = 0; n < 4; ++n) {
            const float p = exp2f((st[rb][n][r] - m) * K2);
            sum += p;
            Ps[prow + n * 16 + fr] = f2bf(p);
          }
          lrow[rb][r] += sum;
        }

      // ---- O += P V  (P rows are this wave's own strip -> no barrier needed)
      __builtin_amdgcn_s_setprio(1);
#pragma unroll
      for (int ks = 0; ks < 2; ++ks) {
        bf16x8 pa0 = *(const bf16x8*)(Ps + (wq * 32 + fr) * PPAD + ks * 32 + fg * 8);
        bf16x8 pa1 = *(const bf16x8*)(Ps + (wq * 32 + 16 + fr) * PPAD + ks * 32 + fg * 8);
#pragma unroll
        for (int n = 0; n < 8; ++n) {
          bf16x8 vbf = *(const bf16x8*)(Vt + (n * 16 + fr) * VPAD + ks * 32 + fg * 8);
          o[0][n] = __builtin_amdgcn_mfma_f32_16x16x32_bf16(pa0, vbf, o[0][n], 0, 0, 0);
          o[1][n] = __builtin_amdgcn_mfma_f32_16x16x32_bf16(pa1, vbf, o[1][n], 0, 0, 0);
        }
      }
      __builtin_amdgcn_s_setprio(0);
    }

    __syncthreads();                        // all waves done reading Ks/Vt
    if (!last) writetile();                 // stage next tile (regs already in flight)
    __syncthreads();                        // staged tile visible
  }

  // ---- epilogue: reduce lane-partial l across fr group, divide, store
#pragma unroll
  for (int rb = 0; rb < 2; ++rb)
#pragma unroll
    for (int r = 0; r < 4; ++r) {
      float l = lrow[rb][r];
      l += __shfl_xor(l, 1, 64);
      l += __shfl_xor(l, 2, 64);
      l += __shfl_xor(l, 4, 64);
      l += __shfl_xor(l, 8, 64);
      const float inv_l = 1.0f / l;
      const int row = qb + wq * 32 + rb * 16 + fg * 4 + r;
#pragma unroll
      for (int n = 0; n < 8; ++n)
        yb[(size_t)(b * SEQ + row) * CDIM + h * HD + n * 16 + fr] = f2bf(o[rb][n][r] * inv_l);
    }
}

// =====================================================================
// kernel_launch
// =====================================================================
extern "C" void kernel_launch(void* const* d_in, const int* in_sizes, int n_in,
                              void* d_out, int out_size, void* d_ws, size_t ws_size,
                              hipStream_t stream) {
  const float* x  = (const float*)d_in[0];
  const float* Wq = (const float*)d_in[1];
  const float* Wk = (const float*)d_in[2];
  const float* Wv = (const float*)d_in[3];
  const float* Wo = (const float*)d_in[4];
  const int*   off = (const int*)d_in[5];
  float* out = (float*)d_out;

  ushort_t* xb  = (ushort_t*)d_ws;                    // [M, C]
  ushort_t* wqb = xb  + (size_t)MTOT * CDIM;          // [C, C]
  ushort_t* wkb = wqb + (size_t)CDIM * CDIM;          // [KVD, C]
  ushort_t* wvb = wkb + (size_t)KVD * CDIM;
  ushort_t* wob = wvb + (size_t)KVD * CDIM;           // [C, C]
  ushort_t* qb_ = wob + (size_t)CDIM * CDIM;          // [M, C]
  ushort_t* kb_ = qb_ + (size_t)MTOT * CDIM;          // [M, KVD]
  ushort_t* vT_ = kb_ + (size_t)MTOT * KVD;           // [KVD, M]  (V^T)
  ushort_t* yb_ = vT_ + (size_t)MTOT * KVD;           // [M, C]
  float2*   tab = (float2*)(yb_ + (size_t)MTOT * CDIM);  // [SEQ, 64] cos/sin

  dim3 blk(256);

  // RoPE table (1 MB)
  rope_table<<<(SEQ * 64 + 255) / 256, blk, 0, stream>>>(tab, off);

  // convert inputs to bf16
  int n8;
  n8 = MTOT * CDIM / 8; cvt_f32_bf16<<<(n8 + 255) / 256, blk, 0, stream>>>(x,  xb,  n8);
  n8 = CDIM * CDIM / 8; cvt_f32_bf16<<<(n8 + 255) / 256, blk, 0, stream>>>(Wq, wqb, n8);
  n8 = KVD  * CDIM / 8; cvt_f32_bf16<<<(n8 + 255) / 256, blk, 0, stream>>>(Wk, wkb, n8);
  n8 = KVD  * CDIM / 8; cvt_f32_bf16<<<(n8 + 255) / 256, blk, 0, stream>>>(Wv, wvb, n8);
  n8 = CDIM * CDIM / 8; cvt_f32_bf16<<<(n8 + 255) / 256, blk, 0, stream>>>(Wo, wob, n8);

  // projections (V written transposed)
  gemm_bt_bf16<0><<<dim3(MTOT / 128, CDIM / 128), blk, 0, stream>>>(xb, wqb, qb_, MTOT, CDIM, CDIM);
  gemm_bt_bf16<0><<<dim3(MTOT / 128, KVD / 128),  blk, 0, stream>>>(xb, wkb, kb_, MTOT, KVD, CDIM);
  gemm_bt_bf16<2><<<dim3(MTOT / 128, KVD / 128),  blk, 0, stream>>>(xb, wvb, vT_, MTOT, KVD, CDIM);

  // RoPE apply (q, k only; vectorized, table-driven)
  rope_apply<<<(MTOT * 20 * 8 + 255) / 256, blk, 0, stream>>>(qb_, kb_, tab);

  // flash attention (BQ=128, heavy-first)
  attn_mfma<<<dim3(BATCH * NH, SEQ / 128), blk, 0, stream>>>(qb_, kb_, vT_, yb_);

  // output projection (fp32 out)
  gemm_bt_bf16<1><<<dim3(MTOT / 128, CDIM / 128), blk, 0, stream>>>(yb_, wob, out, MTOT, CDIM, CDIM);
}